// Round 2
// baseline (142.628 us; speedup 1.0000x reference)
//
#include <hip/hip_runtime.h>
#include <hip/hip_bf16.h>

typedef __attribute__((ext_vector_type(8))) short short8;
typedef __attribute__((ext_vector_type(4))) short short4v;
typedef __attribute__((ext_vector_type(4))) float floatx4;
typedef unsigned short u16;

#define SCL_LOG2E 0.1803368801111204f  // (1/sqrt(64)) * log2(e)

__device__ inline u16 f2b(float f) {
  __hip_bfloat16 h = __float2bfloat16(f);
  union { __hip_bfloat16 h; u16 u; } cv; cv.h = h; return cv.u;
}

// ------- weight prep: fp32 -> bf16 convert + transpose, done ONCE.
// w_qkv [256][768] -> wT1 [768][256]; w_out [256][256] -> wT2 [256][256].
// Grid (16,4): blockIdx.x < 12 handles w_qkv (12 col-blocks), else w_out.
__global__ __launch_bounds__(256) void wprep(const float* __restrict__ w1,
                                             const float* __restrict__ w2,
                                             u16* __restrict__ o1,
                                             u16* __restrict__ o2) {
  __shared__ u16 tile[64][72];
  const int R = 256;
  const float* in; u16* out; int Cc, cb;
  if (blockIdx.x < 12) { in = w1; out = o1; Cc = 768; cb = blockIdx.x; }
  else                 { in = w2; out = o2; Cc = 256; cb = blockIdx.x - 12; }
  int c0 = cb * 64, r0 = blockIdx.y * 64;
  int tx = threadIdx.x, ty = threadIdx.y;  // 16 x 16
#pragma unroll
  for (int i = 0; i < 4; i++) {
    int r = ty + 16 * i;
    float4 v = *(const float4*)&in[(size_t)(r0 + r) * Cc + c0 + tx * 4];
    tile[tx * 4 + 0][r] = f2b(v.x);
    tile[tx * 4 + 1][r] = f2b(v.y);
    tile[tx * 4 + 2][r] = f2b(v.z);
    tile[tx * 4 + 3][r] = f2b(v.w);
  }
  __syncthreads();
#pragma unroll
  for (int i = 0; i < 4; i++) {
    int cc = ty + 16 * i;
    ushort4 o = *(ushort4*)&tile[cc][tx * 4];
    *(ushort4*)&out[(size_t)(c0 + cc) * R + r0 + tx * 4] = o;
  }
}

// ---------------- QKV projection GEMM, fused input transpose.
// A staged from x[b][c][s] fp32 directly (transpose via scalar LDS writes,
// stride 36, double-buffered, reg-prefetch). B loaded directly from wT1
// (pre-transposed bf16, fragment-shaped short8 loads, L2-resident).
__global__ __launch_bounds__(256, 3) void qkv_gemm(const float* __restrict__ x,
                                                   const u16* __restrict__ wT,
                                                   const float* __restrict__ bias,
                                                   u16* __restrict__ Qo,
                                                   u16* __restrict__ Ko,
                                                   u16* __restrict__ Vto) {
  __shared__ u16 As[2][128 * 36];
  const int tid = threadIdx.x, wave = tid >> 6, lane = tid & 63;
  const int l15 = lane & 15, quad = lane >> 4;
  const int wm = (wave >> 1) * 64, wn = (wave & 1) * 64;
  const int m0 = blockIdx.x * 128, n0 = blockIdx.y * 128;
  const int bb = m0 >> 10, s0 = m0 & 1023;
  const int cr = tid >> 3, uu = tid & 7;  // A staging: c-row 0..31, s-segment 0..7

  const float* xrow = x + ((size_t)bb * 256 + cr) * 1024 + s0 + uu * 4;
  const u16* wrow[4];
#pragma unroll
  for (int ni = 0; ni < 4; ni++)
    wrow[ni] = wT + (size_t)(n0 + wn + ni * 16 + l15) * 256 + quad * 8;

  floatx4 acc[4][4] = {};
  float4 LA[4];
  short8 bfr[4], nbf[4];

  // prologue: tile kt=0
#pragma unroll
  for (int r = 0; r < 4; r++) LA[r] = *(const float4*)&xrow[r * 32];
#pragma unroll
  for (int ni = 0; ni < 4; ni++) bfr[ni] = *(const short8*)&wrow[ni][0];
#pragma unroll
  for (int r = 0; r < 4; r++) {
    int s = uu * 4 + r * 32;
    As[0][(s + 0) * 36 + cr] = f2b(LA[r].x);
    As[0][(s + 1) * 36 + cr] = f2b(LA[r].y);
    As[0][(s + 2) * 36 + cr] = f2b(LA[r].z);
    As[0][(s + 3) * 36 + cr] = f2b(LA[r].w);
  }

  int cur = 0;
  for (int kt8 = 0; kt8 < 8; kt8++) {
    const int kt = kt8 * 32;
    if (kt8 < 7) {  // prefetch tile kt+32 into regs
#pragma unroll
      for (int r = 0; r < 4; r++)
        LA[r] = *(const float4*)&xrow[(size_t)(kt + 32) * 1024 + r * 32];
#pragma unroll
      for (int ni = 0; ni < 4; ni++)
        nbf[ni] = *(const short8*)&wrow[ni][kt + 32];
    }
    __syncthreads();  // As[cur] writes visible
    short8 af[4];
#pragma unroll
    for (int mi = 0; mi < 4; mi++) {
      const u16* p = &As[cur][(wm + mi * 16 + l15) * 36 + quad * 8];
      ushort4 lo = *(const ushort4*)p;
      ushort4 hi = *(const ushort4*)(p + 4);
      short8 v;
      v[0] = lo.x; v[1] = lo.y; v[2] = lo.z; v[3] = lo.w;
      v[4] = hi.x; v[5] = hi.y; v[6] = hi.z; v[7] = hi.w;
      af[mi] = v;
    }
#pragma unroll
    for (int mi = 0; mi < 4; mi++)
#pragma unroll
      for (int ni = 0; ni < 4; ni++)
        acc[mi][ni] = __builtin_amdgcn_mfma_f32_16x16x32_bf16(af[mi], bfr[ni],
                                                              acc[mi][ni], 0, 0, 0);
    __syncthreads();  // all reads of As[cur] done
    if (kt8 < 7) {
      u16* d = &As[cur ^ 1][0];
#pragma unroll
      for (int r = 0; r < 4; r++) {
        int s = uu * 4 + r * 32;
        d[(s + 0) * 36 + cr] = f2b(LA[r].x);
        d[(s + 1) * 36 + cr] = f2b(LA[r].y);
        d[(s + 2) * 36 + cr] = f2b(LA[r].z);
        d[(s + 3) * 36 + cr] = f2b(LA[r].w);
      }
#pragma unroll
      for (int ni = 0; ni < 4; ni++) bfr[ni] = nbf[ni];
      cur ^= 1;
    }
  }

#pragma unroll
  for (int ni = 0; ni < 4; ni++) {
    int n = n0 + wn + ni * 16 + l15;
    float bvv = bias[n];
    int h = n / 192;
    int rem = n - h * 192;
#pragma unroll
    for (int mi = 0; mi < 4; mi++) {
      int gm = m0 + wm + mi * 16 + quad * 4;
      int s = gm & 1023;
      if (rem < 128) {
        u16* dst;
        float scl;
        if (rem < 64) { dst = Qo; scl = SCL_LOG2E; } else { dst = Ko; scl = 1.0f; }
        int d = rem & 63;
#pragma unroll
        for (int r = 0; r < 4; r++)
          dst[((size_t)(bb * 4 + h) * 1024 + s + r) * 64 + d] =
              f2b((acc[mi][ni][r] + bvv) * scl);
      } else {
        int d = rem - 128;
        ushort4 pk;
        pk.x = f2b(acc[mi][ni][0] + bvv);
        pk.y = f2b(acc[mi][ni][1] + bvv);
        pk.z = f2b(acc[mi][ni][2] + bvv);
        pk.w = f2b(acc[mi][ni][3] + bvv);
        *(ushort4*)&Vto[((size_t)(bb * 4 + h) * 64 + d) * 1024 + s] = pk;
      }
    }
  }
}

// ---------------- flash attention: double-buffered K/V pipeline (dist-1 reg
// prefetch; K/V are L2-resident so ~200cy latency hides under the ~600cy tile
// compute). LDS 36 KB -> 3 blocks/CU (was 54 KB / 2 blocks). s_setprio around
// MFMA clusters (T5). XCD-pinned grid (bh on blockIdx.x; q-blocks at id-stride
// 64 == same XCD). Transposed formulation: S^T = K·Q^T; exp2(S^T) feeds
// O^T = V^T·P^T directly.
__global__ __launch_bounds__(256, 3) void attn_kern(const u16* __restrict__ Q,
                                                    const u16* __restrict__ K,
                                                    const u16* __restrict__ Vt,
                                                    u16* __restrict__ O) {
  __shared__ u16 kv[2 * 2 * 64 * 72];  // 2 bufs x (K 4608 + V 4608) u16 = 36 KB
  const int bh = blockIdx.x;
  const u16* Qp = Q + (size_t)bh * 64 * 1024;
  const u16* Kp = K + (size_t)bh * 64 * 1024;
  const u16* Vp = Vt + (size_t)bh * 64 * 1024;
  u16* Op = O + (size_t)bh * 64 * 1024;
  const int q0 = blockIdx.y * 128;
  const int tid = threadIdx.x, wave = tid >> 6, lane = tid & 63;
  const int l15 = lane & 15, quad = lane >> 4;

  short8 qa[2][2];
#pragma unroll
  for (int qi = 0; qi < 2; qi++)
#pragma unroll
    for (int kh = 0; kh < 2; kh++)
      qa[qi][kh] = *(const short8*)&Qp[(size_t)(q0 + wave * 32 + qi * 16 + l15) * 64 +
                                       kh * 32 + quad * 8];

  const int srow = tid >> 2;
  const int sc = (tid & 3) * 16;
  const size_t kRow = (size_t)srow * 64 + sc;      // K tile row base (advance by 64*64)
  const size_t vRow = (size_t)srow * 1024 + sc;    // V row base (advance by 64)
  const int lk0 = srow * 72 + sc;                  // LDS K slot
  const int lv0 = 4608 + srow * 72 + sc;           // LDS V slot

  // prologue: tile 0 -> buf0
  {
    short8 t0k0 = *(const short8*)&Kp[kRow];
    short8 t0k1 = *(const short8*)&Kp[kRow + 8];
    short8 t0v0 = *(const short8*)&Vp[vRow];
    short8 t0v1 = *(const short8*)&Vp[vRow + 8];
    *(short8*)&kv[lk0] = t0k0;
    *(short8*)&kv[lk0 + 8] = t0k1;
    *(short8*)&kv[lv0] = t0v0;
    *(short8*)&kv[lv0 + 8] = t0v1;
  }
  __syncthreads();

  float lsum[2] = {0.f, 0.f};
  floatx4 acc[2][4] = {};

  for (int t = 0; t < 16; t++) {
    const u16* Ksb = kv + (t & 1) * 9216;
    const u16* Vsb = Ksb + 4608;

    short8 rk0, rk1, rv0, rv1;
    if (t < 15) {  // issue loads for tile t+1; written after this tile's PV
      size_t ko = kRow + (size_t)(t + 1) * 4096;
      size_t vo = vRow + (size_t)(t + 1) * 64;
      rk0 = *(const short8*)&Kp[ko];
      rk1 = *(const short8*)&Kp[ko + 8];
      rv0 = *(const short8*)&Vp[vo];
      rv1 = *(const short8*)&Vp[vo + 8];
    }

    short8 kb[4][2];
#pragma unroll
    for (int mj = 0; mj < 4; mj++)
#pragma unroll
      for (int kh = 0; kh < 2; kh++)
        kb[mj][kh] = *(const short8*)&Ksb[(mj * 16 + l15) * 72 + kh * 32 + quad * 8];

    floatx4 sf[2][4];
    __builtin_amdgcn_s_setprio(1);
#pragma unroll
    for (int qi = 0; qi < 2; qi++)
#pragma unroll
      for (int mj = 0; mj < 4; mj++) {
        floatx4 z = {};
        z = __builtin_amdgcn_mfma_f32_16x16x32_bf16(kb[mj][0], qa[qi][0], z, 0, 0, 0);
        sf[qi][mj] =
            __builtin_amdgcn_mfma_f32_16x16x32_bf16(kb[mj][1], qa[qi][1], z, 0, 0, 0);
      }
    __builtin_amdgcn_s_setprio(0);

    short4v pb[2][4];
#pragma unroll
    for (int qi = 0; qi < 2; qi++)
#pragma unroll
      for (int mj = 0; mj < 4; mj++) {
        float p0 = exp2f(sf[qi][mj][0]), p1 = exp2f(sf[qi][mj][1]);
        float p2 = exp2f(sf[qi][mj][2]), p3 = exp2f(sf[qi][mj][3]);
        lsum[qi] += (p0 + p1) + (p2 + p3);
        short4v pk;
        pk[0] = (short)f2b(p0); pk[1] = (short)f2b(p1);
        pk[2] = (short)f2b(p2); pk[3] = (short)f2b(p3);
        pb[qi][mj] = pk;
      }

    __builtin_amdgcn_s_setprio(1);
#pragma unroll
    for (int c = 0; c < 4; c++)
#pragma unroll
      for (int md = 0; md < 4; md++) {
        short4v va = *(const short4v*)&Vsb[(md * 16 + l15) * 72 + c * 16 + quad * 4];
#pragma unroll
        for (int qi = 0; qi < 2; qi++)
          acc[qi][md] =
              __builtin_amdgcn_mfma_f32_16x16x16bf16_1k(va, pb[qi][c], acc[qi][md],
                                                        0, 0, 0);
      }
    __builtin_amdgcn_s_setprio(0);

    if (t < 15) {  // write tile t+1 into the other buffer
      u16* dst = kv + ((t + 1) & 1) * 9216;
      *(short8*)&dst[lk0] = rk0;
      *(short8*)&dst[lk0 + 8] = rk1;
      *(short8*)&dst[lv0] = rv0;
      *(short8*)&dst[lv0 + 8] = rv1;
    }
    __syncthreads();
  }

  float inv[2];
#pragma unroll
  for (int qi = 0; qi < 2; qi++) {
    lsum[qi] += __shfl_xor(lsum[qi], 16, 64);
    lsum[qi] += __shfl_xor(lsum[qi], 32, 64);
    inv[qi] = 1.f / lsum[qi];
  }

  // transpose O^T -> O[s][d] through LDS (reuse kv buffer: 128 x 72 u16)
  u16* Ot = kv;
#pragma unroll
  for (int qi = 0; qi < 2; qi++)
#pragma unroll
    for (int md = 0; md < 4; md++) {
      uint2 pk;
      u16 a0 = f2b(acc[qi][md][0] * inv[qi]), a1 = f2b(acc[qi][md][1] * inv[qi]);
      u16 a2 = f2b(acc[qi][md][2] * inv[qi]), a3 = f2b(acc[qi][md][3] * inv[qi]);
      pk.x = (unsigned)a0 | ((unsigned)a1 << 16);
      pk.y = (unsigned)a2 | ((unsigned)a3 << 16);
      *(uint2*)&Ot[(wave * 32 + qi * 16 + l15) * 72 + md * 16 + quad * 4] = pk;
    }
  __syncthreads();
#pragma unroll
  for (int rr = 0; rr < 4; rr++) {
    int row = wave * 32 + (lane >> 3) + 8 * rr;
    int col = (lane & 7) * 8;
    short8 v = *(const short8*)&Ot[row * 72 + col];
    *(short8*)&Op[(size_t)(q0 + row) * 64 + col] = v;
  }
}

// ---------------- output projection + bias + fp32 residual.
// B direct from pre-transposed wT2 (bf16, L2-resident); A single-buffer staged
// with reg-prefetch (write-after-read).
__global__ __launch_bounds__(256) void out_gemm(const u16* __restrict__ Oin,
                                                const u16* __restrict__ wT,
                                                const float* __restrict__ bias,
                                                const float* __restrict__ x,
                                                float* __restrict__ out) {
  __shared__ u16 As[64 * 32];
  const int tid = threadIdx.x, wave = tid >> 6, lane = tid & 63;
  const int l15 = lane & 15, quad = lane >> 4;
  const int wm = (wave >> 1) * 32, wn = (wave & 1) * 64;
  const int m0 = blockIdx.x * 64, n0 = blockIdx.y * 128;
  const int bb = m0 >> 10, s0 = m0 & 1023;
  const int ar = tid >> 2, ach = (tid & 3) * 8;  // A staging

  const u16* wrow[4];
#pragma unroll
  for (int ni = 0; ni < 4; ni++)
    wrow[ni] = wT + (size_t)(n0 + wn + ni * 16 + l15) * 256 + quad * 8;

  floatx4 acc[2][4] = {};
  short8 LA, bfr[4], nbf[4];

  // prologue: tile kt=0
  LA = *(const short8*)&Oin[((size_t)(bb * 4) * 1024 + s0 + ar) * 64 + ach];
#pragma unroll
  for (int ni = 0; ni < 4; ni++) bfr[ni] = *(const short8*)&wrow[ni][0];
  *(short8*)&As[ar * 32 + ach] = LA;

  for (int kt8 = 0; kt8 < 8; kt8++) {
    const int kt = kt8 * 32;
    if (kt8 < 7) {  // prefetch tile kt+32 into regs
      int kn = kt + 32, h = kn >> 6, d0 = kn & 63;
      LA = *(const short8*)&Oin[((size_t)(bb * 4 + h) * 1024 + s0 + ar) * 64 + d0 + ach];
#pragma unroll
      for (int ni = 0; ni < 4; ni++) nbf[ni] = *(const short8*)&wrow[ni][kn];
    }
    __syncthreads();  // As writes visible
    short8 af[2];
#pragma unroll
    for (int mi = 0; mi < 2; mi++)
      af[mi] = *(short8*)&As[(wm + mi * 16 + l15) * 32 + quad * 8];
#pragma unroll
    for (int mi = 0; mi < 2; mi++)
#pragma unroll
      for (int ni = 0; ni < 4; ni++)
        acc[mi][ni] = __builtin_amdgcn_mfma_f32_16x16x32_bf16(af[mi], bfr[ni],
                                                              acc[mi][ni], 0, 0, 0);
    __syncthreads();  // all reads of As done
    if (kt8 < 7) {
      *(short8*)&As[ar * 32 + ach] = LA;
#pragma unroll
      for (int ni = 0; ni < 4; ni++) bfr[ni] = nbf[ni];
    }
  }

#pragma unroll
  for (int ni = 0; ni < 4; ni++) {
    int c = n0 + wn + ni * 16 + l15;
    float bvv = bias[c];
#pragma unroll
    for (int mi = 0; mi < 2; mi++) {
      int gm = m0 + wm + mi * 16 + quad * 4;
      int s = gm & 1023;
      size_t idx = ((size_t)bb * 256 + c) * 1024 + s;
      float4 xr = *(const float4*)&x[idx];
      float4 o;
      o.x = acc[mi][ni][0] + bvv + xr.x;
      o.y = acc[mi][ni][1] + bvv + xr.y;
      o.z = acc[mi][ni][2] + bvv + xr.z;
      o.w = acc[mi][ni][3] + bvv + xr.w;
      *(float4*)&out[idx] = o;
    }
  }
}

extern "C" void kernel_launch(void* const* d_in, const int* in_sizes, int n_in,
                              void* d_out, int out_size, void* d_ws, size_t ws_size,
                              hipStream_t stream) {
  const float* x     = (const float*)d_in[0];
  const float* w_qkv = (const float*)d_in[1];
  const float* b_qkv = (const float*)d_in[2];
  const float* w_out = (const float*)d_in[3];
  const float* b_out = (const float*)d_in[4];
  float* out = (float*)d_out;
  char* ws = (char*)d_ws;

  u16* wT1 = (u16*)(ws);               // 768x256 bf16 = 384 KB
  u16* wT2 = (u16*)(ws + 0x80000);     // 256x256 bf16 = 128 KB
  u16* Qb  = (u16*)(ws + 0x100000);    // 8 MB
  u16* Kb  = (u16*)(ws + 0x900000);    // 8 MB
  u16* Vtb = (u16*)(ws + 0x1100000);   // 8 MB
  u16* Ob  = (u16*)(ws + 0x1900000);   // 8 MB

  wprep<<<dim3(16, 4), dim3(16, 16), 0, stream>>>(w_qkv, w_out, wT1, wT2);
  qkv_gemm<<<dim3(128, 6), 256, 0, stream>>>(x, wT1, b_qkv, Qb, Kb, Vtb);
  attn_kern<<<dim3(64, 8), 256, 0, stream>>>(Qb, Kb, Vtb, Ob);
  out_gemm<<<dim3(256, 2), 256, 0, stream>>>(Ob, wT2, b_out, x, out);
}

// Round 3
// 139.732 us; speedup vs baseline: 1.0207x; 1.0207x over previous
//
#include <hip/hip_runtime.h>
#include <hip/hip_bf16.h>

typedef __attribute__((ext_vector_type(8))) short short8;
typedef __attribute__((ext_vector_type(4))) short short4v;
typedef __attribute__((ext_vector_type(4))) float floatx4;
typedef unsigned short u16;

#define SCL_LOG2E 0.1803368801111204f  // (1/sqrt(64)) * log2(e)

__device__ inline u16 f2b(float f) {
  __hip_bfloat16 h = __float2bfloat16(f);
  union { __hip_bfloat16 h; u16 u; } cv; cv.h = h; return cv.u;
}

// ------- weight prep: fp32 -> bf16 convert + transpose, done ONCE.
// w_qkv [256][768] -> wT1 [768][256]; w_out [256][256] -> wT2 [256][256].
// Grid (16,4): blockIdx.x < 12 handles w_qkv (12 col-blocks), else w_out.
__global__ __launch_bounds__(256) void wprep(const float* __restrict__ w1,
                                             const float* __restrict__ w2,
                                             u16* __restrict__ o1,
                                             u16* __restrict__ o2) {
  __shared__ u16 tile[64][72];
  const int R = 256;
  const float* in; u16* out; int Cc, cb;
  if (blockIdx.x < 12) { in = w1; out = o1; Cc = 768; cb = blockIdx.x; }
  else                 { in = w2; out = o2; Cc = 256; cb = blockIdx.x - 12; }
  int c0 = cb * 64, r0 = blockIdx.y * 64;
  int tx = threadIdx.x, ty = threadIdx.y;  // 16 x 16
#pragma unroll
  for (int i = 0; i < 4; i++) {
    int r = ty + 16 * i;
    float4 v = *(const float4*)&in[(size_t)(r0 + r) * Cc + c0 + tx * 4];
    tile[tx * 4 + 0][r] = f2b(v.x);
    tile[tx * 4 + 1][r] = f2b(v.y);
    tile[tx * 4 + 2][r] = f2b(v.z);
    tile[tx * 4 + 3][r] = f2b(v.w);
  }
  __syncthreads();
#pragma unroll
  for (int i = 0; i < 4; i++) {
    int cc = ty + 16 * i;
    ushort4 o = *(ushort4*)&tile[cc][tx * 4];
    *(ushort4*)&out[(size_t)(c0 + cc) * R + r0 + tx * 4] = o;
  }
}

// ---------------- QKV projection GEMM, fused input transpose.
// A staged from x[b][c][s] fp32 directly (transpose via scalar LDS writes,
// stride 36, double-buffered, reg-prefetch). B loaded directly from wT1
// (pre-transposed bf16, fragment-shaped short8 loads, L2-resident).
__global__ __launch_bounds__(256, 3) void qkv_gemm(const float* __restrict__ x,
                                                   const u16* __restrict__ wT,
                                                   const float* __restrict__ bias,
                                                   u16* __restrict__ Qo,
                                                   u16* __restrict__ Ko,
                                                   u16* __restrict__ Vto) {
  __shared__ u16 As[2][128 * 36];
  const int tid = threadIdx.x, wave = tid >> 6, lane = tid & 63;
  const int l15 = lane & 15, quad = lane >> 4;
  const int wm = (wave >> 1) * 64, wn = (wave & 1) * 64;
  const int m0 = blockIdx.x * 128, n0 = blockIdx.y * 128;
  const int bb = m0 >> 10, s0 = m0 & 1023;
  const int cr = tid >> 3, uu = tid & 7;  // A staging: c-row 0..31, s-segment 0..7

  const float* xrow = x + ((size_t)bb * 256 + cr) * 1024 + s0 + uu * 4;
  const u16* wrow[4];
#pragma unroll
  for (int ni = 0; ni < 4; ni++)
    wrow[ni] = wT + (size_t)(n0 + wn + ni * 16 + l15) * 256 + quad * 8;

  floatx4 acc[4][4] = {};
  float4 LA[4];
  short8 bfr[4], nbf[4];

  // prologue: tile kt=0
#pragma unroll
  for (int r = 0; r < 4; r++) LA[r] = *(const float4*)&xrow[r * 32];
#pragma unroll
  for (int ni = 0; ni < 4; ni++) bfr[ni] = *(const short8*)&wrow[ni][0];
#pragma unroll
  for (int r = 0; r < 4; r++) {
    int s = uu * 4 + r * 32;
    As[0][(s + 0) * 36 + cr] = f2b(LA[r].x);
    As[0][(s + 1) * 36 + cr] = f2b(LA[r].y);
    As[0][(s + 2) * 36 + cr] = f2b(LA[r].z);
    As[0][(s + 3) * 36 + cr] = f2b(LA[r].w);
  }

  int cur = 0;
  for (int kt8 = 0; kt8 < 8; kt8++) {
    const int kt = kt8 * 32;
    if (kt8 < 7) {  // prefetch tile kt+32 into regs
#pragma unroll
      for (int r = 0; r < 4; r++)
        LA[r] = *(const float4*)&xrow[(size_t)(kt + 32) * 1024 + r * 32];
#pragma unroll
      for (int ni = 0; ni < 4; ni++)
        nbf[ni] = *(const short8*)&wrow[ni][kt + 32];
    }
    __syncthreads();  // As[cur] writes visible
    short8 af[4];
#pragma unroll
    for (int mi = 0; mi < 4; mi++) {
      const u16* p = &As[cur][(wm + mi * 16 + l15) * 36 + quad * 8];
      ushort4 lo = *(const ushort4*)p;
      ushort4 hi = *(const ushort4*)(p + 4);
      short8 v;
      v[0] = lo.x; v[1] = lo.y; v[2] = lo.z; v[3] = lo.w;
      v[4] = hi.x; v[5] = hi.y; v[6] = hi.z; v[7] = hi.w;
      af[mi] = v;
    }
#pragma unroll
    for (int mi = 0; mi < 4; mi++)
#pragma unroll
      for (int ni = 0; ni < 4; ni++)
        acc[mi][ni] = __builtin_amdgcn_mfma_f32_16x16x32_bf16(af[mi], bfr[ni],
                                                              acc[mi][ni], 0, 0, 0);
    __syncthreads();  // all reads of As[cur] done
    if (kt8 < 7) {
      u16* d = &As[cur ^ 1][0];
#pragma unroll
      for (int r = 0; r < 4; r++) {
        int s = uu * 4 + r * 32;
        d[(s + 0) * 36 + cr] = f2b(LA[r].x);
        d[(s + 1) * 36 + cr] = f2b(LA[r].y);
        d[(s + 2) * 36 + cr] = f2b(LA[r].z);
        d[(s + 3) * 36 + cr] = f2b(LA[r].w);
      }
#pragma unroll
      for (int ni = 0; ni < 4; ni++) bfr[ni] = nbf[ni];
      cur ^= 1;
    }
  }

#pragma unroll
  for (int ni = 0; ni < 4; ni++) {
    int n = n0 + wn + ni * 16 + l15;
    float bvv = bias[n];
    int h = n / 192;
    int rem = n - h * 192;
#pragma unroll
    for (int mi = 0; mi < 4; mi++) {
      int gm = m0 + wm + mi * 16 + quad * 4;
      int s = gm & 1023;
      if (rem < 128) {
        u16* dst;
        float scl;
        if (rem < 64) { dst = Qo; scl = SCL_LOG2E; } else { dst = Ko; scl = 1.0f; }
        int d = rem & 63;
#pragma unroll
        for (int r = 0; r < 4; r++)
          dst[((size_t)(bb * 4 + h) * 1024 + s + r) * 64 + d] =
              f2b((acc[mi][ni][r] + bvv) * scl);
      } else {
        int d = rem - 128;
        ushort4 pk;
        pk.x = f2b(acc[mi][ni][0] + bvv);
        pk.y = f2b(acc[mi][ni][1] + bvv);
        pk.z = f2b(acc[mi][ni][2] + bvv);
        pk.w = f2b(acc[mi][ni][3] + bvv);
        *(ushort4*)&Vto[((size_t)(bb * 4 + h) * 64 + d) * 1024 + s] = pk;
      }
    }
  }
}

// ---------------- flash attention: tri-buffered K/V pipeline (prefetch dist 2),
// XCD-pinned grid (bh on blockIdx.x; 8 q-blocks per bh at id-stride 64 == same XCD).
// Transposed formulation: S^T = K·Q^T; exp2(S^T) feeds O^T = V^T·P^T directly.
__global__ __launch_bounds__(256, 2) void attn_kern(const u16* __restrict__ Q,
                                                    const u16* __restrict__ K,
                                                    const u16* __restrict__ Vt,
                                                    u16* __restrict__ O) {
  __shared__ u16 kv[3 * 2 * 64 * 72];  // 3 bufs x (K 4608 + V 4608) u16 = 54 KB
  const int bh = blockIdx.x;
  const u16* Qp = Q + (size_t)bh * 64 * 1024;
  const u16* Kp = K + (size_t)bh * 64 * 1024;
  const u16* Vp = Vt + (size_t)bh * 64 * 1024;
  u16* Op = O + (size_t)bh * 64 * 1024;
  const int q0 = blockIdx.y * 128;
  const int tid = threadIdx.x, wave = tid >> 6, lane = tid & 63;
  const int l15 = lane & 15, quad = lane >> 4;

  short8 qa[2][2];
#pragma unroll
  for (int qi = 0; qi < 2; qi++)
#pragma unroll
    for (int kh = 0; kh < 2; kh++)
      qa[qi][kh] = *(const short8*)&Qp[(size_t)(q0 + wave * 32 + qi * 16 + l15) * 64 +
                                       kh * 32 + quad * 8];

  const int srow = tid >> 2;
  const int sc = (tid & 3) * 16;
  const size_t kRow = (size_t)srow * 64 + sc;      // K tile row base (advance by 64*64)
  const size_t vRow = (size_t)srow * 1024 + sc;    // V row base (advance by 64)

  // prologue: tiles 0,1 -> buf0,buf1; tile 2 loads -> regs r1
  short8 t0k0 = *(const short8*)&Kp[kRow];
  short8 t0k1 = *(const short8*)&Kp[kRow + 8];
  short8 t0v0 = *(const short8*)&Vp[vRow];
  short8 t0v1 = *(const short8*)&Vp[vRow + 8];
  short8 t1k0 = *(const short8*)&Kp[kRow + 4096];
  short8 t1k1 = *(const short8*)&Kp[kRow + 4096 + 8];
  short8 t1v0 = *(const short8*)&Vp[vRow + 64];
  short8 t1v1 = *(const short8*)&Vp[vRow + 64 + 8];
  short8 r1k0 = *(const short8*)&Kp[kRow + 8192];
  short8 r1k1 = *(const short8*)&Kp[kRow + 8192 + 8];
  short8 r1v0 = *(const short8*)&Vp[vRow + 128];
  short8 r1v1 = *(const short8*)&Vp[vRow + 128 + 8];
  *(short8*)&kv[srow * 72 + sc] = t0k0;
  *(short8*)&kv[srow * 72 + sc + 8] = t0k1;
  *(short8*)&kv[4608 + srow * 72 + sc] = t0v0;
  *(short8*)&kv[4608 + srow * 72 + sc + 8] = t0v1;
  *(short8*)&kv[9216 + srow * 72 + sc] = t1k0;
  *(short8*)&kv[9216 + srow * 72 + sc + 8] = t1k1;
  *(short8*)&kv[9216 + 4608 + srow * 72 + sc] = t1v0;
  *(short8*)&kv[9216 + 4608 + srow * 72 + sc + 8] = t1v1;
  __syncthreads();

  float lsum[2] = {0.f, 0.f};
  floatx4 acc[2][4] = {};

  int cur = 0;   // buffer holding tile t
  int wr = 2;    // buffer to write tile t+2 into
  for (int t = 0; t < 16; t++) {
    const u16* Ksb = kv + cur * 9216;
    const u16* Vsb = Ksb + 4608;

    short8 r2k0, r2k1, r2v0, r2v1;
    if (t < 13) {  // issue loads for tile t+3 (waited at end of t+1)
      size_t ko = kRow + (size_t)(t + 3) * 4096;
      size_t vo = vRow + (size_t)(t + 3) * 64;
      r2k0 = *(const short8*)&Kp[ko];
      r2k1 = *(const short8*)&Kp[ko + 8];
      r2v0 = *(const short8*)&Vp[vo];
      r2v1 = *(const short8*)&Vp[vo + 8];
    }

    short8 kb[4][2];
#pragma unroll
    for (int mj = 0; mj < 4; mj++)
#pragma unroll
      for (int kh = 0; kh < 2; kh++)
        kb[mj][kh] = *(const short8*)&Ksb[(mj * 16 + l15) * 72 + kh * 32 + quad * 8];

    floatx4 sf[2][4];
#pragma unroll
    for (int qi = 0; qi < 2; qi++)
#pragma unroll
      for (int mj = 0; mj < 4; mj++) {
        floatx4 z = {};
        z = __builtin_amdgcn_mfma_f32_16x16x32_bf16(kb[mj][0], qa[qi][0], z, 0, 0, 0);
        sf[qi][mj] =
            __builtin_amdgcn_mfma_f32_16x16x32_bf16(kb[mj][1], qa[qi][1], z, 0, 0, 0);
      }

    short4v pb[2][4];
#pragma unroll
    for (int qi = 0; qi < 2; qi++)
#pragma unroll
      for (int mj = 0; mj < 4; mj++) {
        float p0 = exp2f(sf[qi][mj][0]), p1 = exp2f(sf[qi][mj][1]);
        float p2 = exp2f(sf[qi][mj][2]), p3 = exp2f(sf[qi][mj][3]);
        lsum[qi] += (p0 + p1) + (p2 + p3);
        short4v pk;
        pk[0] = (short)f2b(p0); pk[1] = (short)f2b(p1);
        pk[2] = (short)f2b(p2); pk[3] = (short)f2b(p3);
        pb[qi][mj] = pk;
      }

#pragma unroll
    for (int c = 0; c < 4; c++)
#pragma unroll
      for (int md = 0; md < 4; md++) {
        short4v va = *(const short4v*)&Vsb[(md * 16 + l15) * 72 + c * 16 + quad * 4];
#pragma unroll
        for (int qi = 0; qi < 2; qi++)
          acc[qi][md] =
              __builtin_amdgcn_mfma_f32_16x16x16bf16_1k(va, pb[qi][c], acc[qi][md],
                                                        0, 0, 0);
      }

    if (t < 14) {  // write tile t+2 (loads issued at iteration t-1) into buf wr
      u16* dst = kv + wr * 9216;
      *(short8*)&dst[srow * 72 + sc] = r1k0;
      *(short8*)&dst[srow * 72 + sc + 8] = r1k1;
      *(short8*)&dst[4608 + srow * 72 + sc] = r1v0;
      *(short8*)&dst[4608 + srow * 72 + sc + 8] = r1v1;
    }
    r1k0 = r2k0; r1k1 = r2k1; r1v0 = r2v0; r1v1 = r2v1;
    cur = (cur == 2) ? 0 : cur + 1;
    wr = (wr == 2) ? 0 : wr + 1;
    __syncthreads();
  }

  float inv[2];
#pragma unroll
  for (int qi = 0; qi < 2; qi++) {
    lsum[qi] += __shfl_xor(lsum[qi], 16, 64);
    lsum[qi] += __shfl_xor(lsum[qi], 32, 64);
    inv[qi] = 1.f / lsum[qi];
  }

  // transpose O^T -> O[s][d] through LDS (reuse kv buffer: 128 x 72 u16)
  u16* Ot = kv;
#pragma unroll
  for (int qi = 0; qi < 2; qi++)
#pragma unroll
    for (int md = 0; md < 4; md++) {
      uint2 pk;
      u16 a0 = f2b(acc[qi][md][0] * inv[qi]), a1 = f2b(acc[qi][md][1] * inv[qi]);
      u16 a2 = f2b(acc[qi][md][2] * inv[qi]), a3 = f2b(acc[qi][md][3] * inv[qi]);
      pk.x = (unsigned)a0 | ((unsigned)a1 << 16);
      pk.y = (unsigned)a2 | ((unsigned)a3 << 16);
      *(uint2*)&Ot[(wave * 32 + qi * 16 + l15) * 72 + md * 16 + quad * 4] = pk;
    }
  __syncthreads();
#pragma unroll
  for (int rr = 0; rr < 4; rr++) {
    int row = wave * 32 + (lane >> 3) + 8 * rr;
    int col = (lane & 7) * 8;
    short8 v = *(const short8*)&Ot[row * 72 + col];
    *(short8*)&Op[(size_t)(q0 + row) * 64 + col] = v;
  }
}

// ---------------- output projection + bias + fp32 residual.
// B direct from pre-transposed wT2 (bf16, L2-resident); A single-buffer staged
// with reg-prefetch (write-after-read).
__global__ __launch_bounds__(256) void out_gemm(const u16* __restrict__ Oin,
                                                const u16* __restrict__ wT,
                                                const float* __restrict__ bias,
                                                const float* __restrict__ x,
                                                float* __restrict__ out) {
  __shared__ u16 As[64 * 32];
  const int tid = threadIdx.x, wave = tid >> 6, lane = tid & 63;
  const int l15 = lane & 15, quad = lane >> 4;
  const int wm = (wave >> 1) * 32, wn = (wave & 1) * 64;
  const int m0 = blockIdx.x * 64, n0 = blockIdx.y * 128;
  const int bb = m0 >> 10, s0 = m0 & 1023;
  const int ar = tid >> 2, ach = (tid & 3) * 8;  // A staging

  const u16* wrow[4];
#pragma unroll
  for (int ni = 0; ni < 4; ni++)
    wrow[ni] = wT + (size_t)(n0 + wn + ni * 16 + l15) * 256 + quad * 8;

  floatx4 acc[2][4] = {};
  short8 LA, bfr[4], nbf[4];

  // prologue: tile kt=0
  LA = *(const short8*)&Oin[((size_t)(bb * 4) * 1024 + s0 + ar) * 64 + ach];
#pragma unroll
  for (int ni = 0; ni < 4; ni++) bfr[ni] = *(const short8*)&wrow[ni][0];
  *(short8*)&As[ar * 32 + ach] = LA;

  for (int kt8 = 0; kt8 < 8; kt8++) {
    const int kt = kt8 * 32;
    if (kt8 < 7) {  // prefetch tile kt+32 into regs
      int kn = kt + 32, h = kn >> 6, d0 = kn & 63;
      LA = *(const short8*)&Oin[((size_t)(bb * 4 + h) * 1024 + s0 + ar) * 64 + d0 + ach];
#pragma unroll
      for (int ni = 0; ni < 4; ni++) nbf[ni] = *(const short8*)&wrow[ni][kn];
    }
    __syncthreads();  // As writes visible
    short8 af[2];
#pragma unroll
    for (int mi = 0; mi < 2; mi++)
      af[mi] = *(short8*)&As[(wm + mi * 16 + l15) * 32 + quad * 8];
#pragma unroll
    for (int mi = 0; mi < 2; mi++)
#pragma unroll
      for (int ni = 0; ni < 4; ni++)
        acc[mi][ni] = __builtin_amdgcn_mfma_f32_16x16x32_bf16(af[mi], bfr[ni],
                                                              acc[mi][ni], 0, 0, 0);
    __syncthreads();  // all reads of As done
    if (kt8 < 7) {
      *(short8*)&As[ar * 32 + ach] = LA;
#pragma unroll
      for (int ni = 0; ni < 4; ni++) bfr[ni] = nbf[ni];
    }
  }

#pragma unroll
  for (int ni = 0; ni < 4; ni++) {
    int c = n0 + wn + ni * 16 + l15;
    float bvv = bias[c];
#pragma unroll
    for (int mi = 0; mi < 2; mi++) {
      int gm = m0 + wm + mi * 16 + quad * 4;
      int s = gm & 1023;
      size_t idx = ((size_t)bb * 256 + c) * 1024 + s;
      float4 xr = *(const float4*)&x[idx];
      float4 o;
      o.x = acc[mi][ni][0] + bvv + xr.x;
      o.y = acc[mi][ni][1] + bvv + xr.y;
      o.z = acc[mi][ni][2] + bvv + xr.z;
      o.w = acc[mi][ni][3] + bvv + xr.w;
      *(float4*)&out[idx] = o;
    }
  }
}

extern "C" void kernel_launch(void* const* d_in, const int* in_sizes, int n_in,
                              void* d_out, int out_size, void* d_ws, size_t ws_size,
                              hipStream_t stream) {
  const float* x     = (const float*)d_in[0];
  const float* w_qkv = (const float*)d_in[1];
  const float* b_qkv = (const float*)d_in[2];
  const float* w_out = (const float*)d_in[3];
  const float* b_out = (const float*)d_in[4];
  float* out = (float*)d_out;
  char* ws = (char*)d_ws;

  u16* wT1 = (u16*)(ws);               // 768x256 bf16 = 384 KB
  u16* wT2 = (u16*)(ws + 0x80000);     // 256x256 bf16 = 128 KB
  u16* Qb  = (u16*)(ws + 0x100000);    // 8 MB
  u16* Kb  = (u16*)(ws + 0x900000);    // 8 MB
  u16* Vtb = (u16*)(ws + 0x1100000);   // 8 MB
  u16* Ob  = (u16*)(ws + 0x1900000);   // 8 MB

  wprep<<<dim3(16, 4), dim3(16, 16), 0, stream>>>(w_qkv, w_out, wT1, wT2);
  qkv_gemm<<<dim3(128, 6), 256, 0, stream>>>(x, wT1, b_qkv, Qb, Kb, Vtb);
  attn_kern<<<dim3(64, 8), 256, 0, stream>>>(Qb, Kb, Vtb, Ob);
  out_gemm<<<dim3(256, 2), 256, 0, stream>>>(Ob, wT2, b_out, x, out);
}